// Round 10
// baseline (307.322 us; speedup 1.0000x reference)
//
#include <hip/hip_runtime.h>
#include <math.h>

#define TSEQ   2048
#define NBATCH 4
#define NHEAD  16
#define HDIM   64
#define DMODEL 1024
#define MROWS  (NBATCH * TSEQ)   // 8192
// fold 8 * log2(e) into Q so softmax runs in exp2 domain (v_exp_f32 native)
#define QSCALE 11.541560327111707f

typedef float f32x4  __attribute__((ext_vector_type(4)));
typedef _Float16 f16x8 __attribute__((ext_vector_type(8)));

// RNE f32 pair -> packed 2x f16 in a u32
static __device__ __forceinline__ unsigned pkh(float a, float b) {
    union { _Float16 h[2]; unsigned u; } z;
    z.h[0] = (_Float16)a; z.h[1] = (_Float16)b;
    return z.u;
}

// async global->LDS, 16B per lane; LDS dest = wave-uniform base + lane*16
static __device__ __forceinline__ void async_copy16(void* lds, const void* g) {
    __builtin_amdgcn_global_load_lds(
        (const __attribute__((address_space(1))) void*)g,
        (__attribute__((address_space(3))) void*)lds, 16, 0, 0);
}

// ---------------------------------------------------------------------------
// fp32 -> split-fp16 for X (hi + residual), fp16 for W.
// ---------------------------------------------------------------------------
#define X_F4 (MROWS * DMODEL / 4)          // 2097152
#define W_F4 (DMODEL * DMODEL / 4)         // 262144  (1<<18)
__global__ __launch_bounds__(256) void cast_all(
    const float* __restrict__ x,
    const float* __restrict__ wq, const float* __restrict__ wk,
    const float* __restrict__ wv,
    _Float16* __restrict__ X16, _Float16* __restrict__ Xr,
    _Float16* __restrict__ Wf)   // Wf [3][D][D]
{
    int gid = blockIdx.x * 256 + threadIdx.x;
    if (gid < X_F4) {
        float4 v = ((const float4*)x)[gid];
        float f[4] = {v.x, v.y, v.z, v.w};
        _Float16 h[4], r[4];
        #pragma unroll
        for (int c = 0; c < 4; c++) {
            h[c] = (_Float16)f[c];
            r[c] = (_Float16)(f[c] - (float)h[c]);
        }
        *(float2*)(X16 + (size_t)gid * 4) = *(const float2*)h;
        *(float2*)(Xr  + (size_t)gid * 4) = *(const float2*)r;
    } else {
        int rr = gid - X_F4;
        int z = rr >> 18;                  // 0..2
        int off = rr & (W_F4 - 1);
        const float* src = (z == 0) ? wq : (z == 1) ? wk : wv;
        _Float16* dst = Wf + (size_t)z * DMODEL * DMODEL;
        float4 v = ((const float4*)src)[off];
        _Float16 h[4] = {(_Float16)v.x, (_Float16)v.y, (_Float16)v.z, (_Float16)v.w};
        *(float2*)(dst + (size_t)off * 4) = *(const float2*)h;
    }
}

// ---------------------------------------------------------------------------
// Split-fp16 MFMA GEMM: Y = X W^T + b.
// R10: BK=64 — 16 K-steps (was 32), 2 barriers each -> half the barrier
// crossings; 64 MFMA/wave per staged phase (was 32). Staging geometry is
// the attn pattern: [128][64] planes, write chunk chsw=(lane&7)^((lane>>3)&7)
// at slot lane&7 of row lane>>3 (per 8-row group); read chunk g at slot
// g^(t&7). LDS 48 KB -> 3 blocks/CU; per-kk fragment loads keep VGPR ~130.
// z0/z1: 2 MFMA (X16*W + Xr*W); z2 (V): 1 MFMA. XCD swizzle (T1) kept.
// ---------------------------------------------------------------------------
__global__ __launch_bounds__(256, 3) void qkv_gemm_mfma(
    const _Float16* __restrict__ X16, const _Float16* __restrict__ Xr,
    const _Float16* __restrict__ Wf3,
    const float* __restrict__ bq, const float* __restrict__ bk,
    const float* __restrict__ bv,
    _Float16* __restrict__ Qh, _Float16* __restrict__ Qr,
    _Float16* __restrict__ Kh, _Float16* __restrict__ Kr,
    _Float16* __restrict__ VgT)
{
    const int z = blockIdx.z;
    const bool dor = (z != 2);             // residual A-plane for Q,K only
    const _Float16* W = Wf3 + (size_t)z * DMODEL * DMODEL;
    const float* bias = (z == 0) ? bq : (z == 1) ? bk : bv;

    __shared__ __align__(16) _Float16 Ah[128 * 64];
    __shared__ __align__(16) _Float16 Ar[128 * 64];
    __shared__ __align__(16) _Float16 Bh[128 * 64];

    const int tid  = threadIdx.x;
    const int w    = tid >> 6;
    const int lane = tid & 63;
    const int t    = lane & 15;
    const int quad = lane >> 4;
    const int wm   = w >> 1, wn = w & 1;

    // XCD-chunked swizzle: orig in hw dispatch order (x fastest), 512 blocks
    const int orig = blockIdx.x + (blockIdx.y << 3);       // 0..511
    const int nw   = (orig & 7) * 64 + (orig >> 3);        // bijective remap
    const int bm   = (nw >> 3) * 128;                      // m-tile 0..63
    const int bn   = (nw & 7) * 128;                       // n-tile 0..7

    // staging geometry (attn pattern): 256 lanes x 16B = 32 rows of 128B/pass
    const int rl     = w * 8 + (lane >> 3);                // 0..31
    const int chsw   = (lane & 7) ^ ((lane >> 3) & 7);
    const int ld_off = (w * 8) * 64;                       // wave-uniform base

    // read slots: chunk g = kk*4 + quad at slot (g^(t&7))*8
    const int rq0 = ((0 * 4 + quad) ^ (t & 7)) * 8;
    const int rq1 = ((1 * 4 + quad) ^ (t & 7)) * 8;

    f32x4 acc[4][4];
    #pragma unroll
    for (int i = 0; i < 4; i++)
        #pragma unroll
        for (int j = 0; j < 4; j++) acc[i][j] = (f32x4){0.f, 0.f, 0.f, 0.f};

    for (int k0 = 0; k0 < DMODEL; k0 += 64) {
        __syncthreads();
        #pragma unroll
        for (int i = 0; i < 4; i++) {
            int row  = i * 32 + rl;
            int ldst = (i * 32) * 64 + ld_off;
            size_t ga = (size_t)(bm + row) * DMODEL + k0 + chsw * 8;
            size_t gb = (size_t)(bn + row) * DMODEL + k0 + chsw * 8;
            async_copy16(&Ah[ldst], X16 + ga);
            async_copy16(&Bh[ldst], W + gb);
            if (dor) async_copy16(&Ar[ldst], Xr + ga);
        }
        __syncthreads();

        #pragma unroll
        for (int kk = 0; kk < 2; kk++) {
            const int rq = kk ? rq1 : rq0;
            f16x8 ah[4], ar[4], bh[4];
            #pragma unroll
            for (int mt = 0; mt < 4; mt++) {
                int off = (wm * 64 + mt * 16 + t) * 64 + rq;
                ah[mt] = *(const f16x8*)&Ah[off];
                if (dor) ar[mt] = *(const f16x8*)&Ar[off];
            }
            #pragma unroll
            for (int nt = 0; nt < 4; nt++) {
                int off = (wn * 64 + nt * 16 + t) * 64 + rq;
                bh[nt] = *(const f16x8*)&Bh[off];
            }
            #pragma unroll
            for (int mt = 0; mt < 4; mt++)
                #pragma unroll
                for (int nt = 0; nt < 4; nt++) {
                    if (dor)
                        acc[mt][nt] = __builtin_amdgcn_mfma_f32_16x16x32_f16(
                            ar[mt], bh[nt], acc[mt][nt], 0, 0, 0);
                    acc[mt][nt] = __builtin_amdgcn_mfma_f32_16x16x32_f16(
                        ah[mt], bh[nt], acc[mt][nt], 0, 0, 0);
                }
        }
    }

    const float scale = (z == 0) ? QSCALE : 1.0f;
    const int n_base = bn + wn * 64;
    const int h_head = n_base >> 6;
    float bvs[4];
    #pragma unroll
    for (int nt = 0; nt < 4; nt++)
        bvs[nt] = bias[n_base + nt * 16 + t];

    #pragma unroll
    for (int mt = 0; mt < 4; mt++) {
        #pragma unroll
        for (int r = 0; r < 4; r++) {
            int m  = bm + wm * 64 + mt * 16 + quad * 4 + r;
            int b_ = m >> 11;
            int t_ = m & 2047;
            #pragma unroll
            for (int nt = 0; nt < 4; nt++) {
                int d = nt * 16 + t;
                float v = (acc[mt][nt][r] + bvs[nt]) * scale;
                if (z == 2) {
                    size_t idx = ((size_t)(b_ * NHEAD + h_head) * HDIM + d) * TSEQ + t_;
                    VgT[idx] = (_Float16)v;
                } else {
                    size_t idx = (((size_t)(b_ * NHEAD + h_head) * TSEQ + t_) << 6) + d;
                    _Float16 hb = (_Float16)v;
                    _Float16 rb = (_Float16)(v - (float)hb);
                    if (z == 0) { Qh[idx] = hb; Qr[idx] = rb; }
                    else        { Kh[idx] = hb; Kr[idx] = rb; }
                }
            }
        }
    }
}

// ---------------------------------------------------------------------------
// MFMA flash attention v10 — fp16-split Q/K (unchanged from R9).
//  Swapped QK^T 3-MFMA split: S = kh*qr + kr*qh + kh*qh (drop kr*qr ~2^-24).
//  In-register P, defer-max, setprio; 1024-block heavy-first grid.
// LDS: 2*(8+8+8) = 48 KB -> 3 blocks/CU.
// ---------------------------------------------------------------------------
__global__ __launch_bounds__(256, 3) void attn_fwd(
    const _Float16* __restrict__ Qh, const _Float16* __restrict__ Qr,
    const _Float16* __restrict__ Kh, const _Float16* __restrict__ Kr,
    const _Float16* __restrict__ VgT,   // [bh][64][T]
    float* __restrict__ out)            // [B][T][1024]
{
    __shared__ __align__(16) _Float16 Kh_lds[2][64 * 64];
    __shared__ __align__(16) _Float16 Kr_lds[2][64 * 64];
    __shared__ __align__(16) _Float16 Vt_lds[2][64 * 64];

    const int tid  = threadIdx.x;

    // heavy-first XCD-chunked mapping over 1024 blocks
    const int l    = blockIdx.x;
    const int xcd  = l & 7;
    const int idx  = l >> 3;                 // 0..127
    const int bh   = xcd * 8 + (idx & 7);    // 0..63
    const int qb   = 15 - (idx >> 3);        // 15..0 (heavy first)

    const int b    = bh >> 4, h = bh & 15;
    const int w    = tid >> 6;
    const int lane = tid & 63;
    const int t    = lane & 15;
    const int quad = lane >> 4;

    // staging geometry: per round, 256 lanes x 16B = 32 rows of 128B.
    const int rl      = w * 8 + (lane >> 3);         // 0..31 within round
    const int chsw    = (lane & 7) ^ ((lane >> 3) & 7);
    const int ld_off  = (w * 8) * 64;                // wave-uniform LDS base

    const size_t kbase = (size_t)bh * TSEQ;          // K rows
    const size_t vbase = (size_t)bh * HDIM;          // V^T rows

    // K read chunks: logical chunk g = dh*4+quad at slot g^(t&7)
    const int rs0 = ((0 * 4 + quad) ^ (t & 7)) * 8;
    const int rs1 = ((1 * 4 + quad) ^ (t & 7)) * 8;
    // V read chunks for PV: quad bits SWAPPED (absorbs the 2nd exchange step)
    const int qsw = ((quad & 1) << 1) | (quad >> 1);
    const int rp0 = ((0 * 4 + qsw) ^ (t & 7)) * 8;
    const int rp1 = ((1 * 4 + qsw) ^ (t & 7)) * 8;
    const bool hi4 = (quad & 1);                     // lane bit4

    f16x8 ones;
    #pragma unroll
    for (int i = 0; i < 8; i++) ones[i] = (_Float16)1.0f;

    auto stage = [&](int kt, int bf) {
        #pragma unroll
        for (int i = 0; i < 2; i++) {
            int row = i * 32 + rl;
            const _Float16* gk = Kh + (kbase + kt * 64 + row) * 64 + chsw * 8;
            async_copy16(&Kh_lds[bf][(i * 32) * 64 + ld_off], gk);
            const _Float16* gr = Kr + (kbase + kt * 64 + row) * 64 + chsw * 8;
            async_copy16(&Kr_lds[bf][(i * 32) * 64 + ld_off], gr);
            const _Float16* gv = VgT + (vbase + row) * TSEQ + kt * 64 + chsw * 8;
            async_copy16(&Vt_lds[bf][(i * 32) * 64 + ld_off], gv);
        }
    };

    // Q frags (used as B-operand in swapped QK^T)
    f16x8 qh[2][2], qr[2][2];
    #pragma unroll
    for (int mt = 0; mt < 2; mt++) {
        size_t qrow = kbase + qb * 128 + w * 32 + mt * 16 + t;
        #pragma unroll
        for (int dh = 0; dh < 2; dh++) {
            qh[mt][dh] = *(const f16x8*)(Qh + qrow * 64 + dh * 32 + quad * 8);
            qr[mt][dh] = *(const f16x8*)(Qr + qrow * 64 + dh * 32 + quad * 8);
        }
    }

    f32x4 O[2][4], Ol[2];
    #pragma unroll
    for (int mt = 0; mt < 2; mt++) {
        Ol[mt] = (f32x4){0.f, 0.f, 0.f, 0.f};
        #pragma unroll
        for (int j = 0; j < 4; j++) O[mt][j] = (f32x4){0.f, 0.f, 0.f, 0.f};
    }
    float m_st[2];
    m_st[0] = -1e30f; m_st[1] = -1e30f;

    const int npair = qb + 1;

    #pragma unroll 1
    for (int p = 0; p < npair; p++) {
        __syncthreads();              // previous pair's LDS reads complete
        stage(2 * p, 0);
        stage(2 * p + 1, 1);
        __syncthreads();              // drain the 12 async copies

        #pragma unroll
        for (int mt = 0; mt < 2; mt++) {
            // ---- S^T over 128 kv: S[c8][r] = S[kp=c8*16+quad*4+r][q=t]
            f32x4 S[8];
            __builtin_amdgcn_s_setprio(1);
            #pragma unroll
            for (int c8 = 0; c8 < 8; c8++) {
                S[c8] = (f32x4){0.f, 0.f, 0.f, 0.f};
                const int bf = c8 >> 2;
                const int rowoff = ((c8 & 3) * 16 + t) * 64;
                {
                    f16x8 kh = *(const f16x8*)&Kh_lds[bf][rowoff + rs0];
                    f16x8 kr = *(const f16x8*)&Kr_lds[bf][rowoff + rs0];
                    S[c8] = __builtin_amdgcn_mfma_f32_16x16x32_f16(kh, qr[mt][0], S[c8], 0, 0, 0);
                    S[c8] = __builtin_amdgcn_mfma_f32_16x16x32_f16(kr, qh[mt][0], S[c8], 0, 0, 0);
                    S[c8] = __builtin_amdgcn_mfma_f32_16x16x32_f16(kh, qh[mt][0], S[c8], 0, 0, 0);
                }
                {
                    f16x8 kh = *(const f16x8*)&Kh_lds[bf][rowoff + rs1];
                    f16x8 kr = *(const f16x8*)&Kr_lds[bf][rowoff + rs1];
                    S[c8] = __builtin_amdgcn_mfma_f32_16x16x32_f16(kh, qr[mt][1], S[c8], 0, 0, 0);
                    S[c8] = __builtin_amdgcn_mfma_f32_16x16x32_f16(kr, qh[mt][1], S[c8], 0, 0, 0);
                    S[c8] = __builtin_amdgcn_mfma_f32_16x16x32_f16(kh, qh[mt][1], S[c8], 0, 0, 0);
                }
            }
            __builtin_amdgcn_s_setprio(0);

            // causal mask: kp > q  (only the diagonal pair)
            if (p == qb) {
                const int qloc = w * 32 + mt * 16 + t;
                #pragma unroll
                for (int c8 = 0; c8 < 8; c8++) {
                    int kp = c8 * 16 + quad * 4;
                    #pragma unroll
                    for (int r = 0; r < 4; r++)
                        if (kp + r > qloc) S[c8][r] = -1e30f;
                }
            }

            // ---- row max: in-lane over 32 + cross-quad (2 shfl) ----
            float mx = S[0][0];
            #pragma unroll
            for (int c8 = 0; c8 < 8; c8++)
                #pragma unroll
                for (int r = 0; r < 4; r++)
                    mx = fmaxf(mx, S[c8][r]);
            mx = fmaxf(mx, __shfl_xor(mx, 16));
            mx = fmaxf(mx, __shfl_xor(mx, 32));

            // ---- defer-max rescale (THR=8 in exp2 domain) ----
            bool need = mx > m_st[mt] + 8.0f;
            if (__ballot(need)) {
                float mn = fmaxf(m_st[mt], mx);
                float al = exp2f(m_st[mt] - mn);
                m_st[mt] = mn;
                #pragma unroll
                for (int r = 0; r < 4; r++) {
                    // O rows live at q = quad*4+r; al lives at lane t=q
                    float a = __shfl(al, (lane & 48) + quad * 4 + r);
                    Ol[mt][r] *= a;
                    #pragma unroll
                    for (int ct2 = 0; ct2 < 4; ct2++) O[mt][ct2][r] *= a;
                }
            }

            #pragma unroll
            for (int c8 = 0; c8 < 8; c8++)
                #pragma unroll
                for (int r = 0; r < 4; r++)
                    S[c8][r] = exp2f(S[c8][r] - m_st[mt]);

            // ---- pack P to f16 pairs: P2[c8][rp] = (r=2rp, r=2rp+1) ----
            unsigned P2[8][2];
            #pragma unroll
            for (int c8 = 0; c8 < 8; c8++) {
                P2[c8][0] = pkh(S[c8][0], S[c8][1]);
                P2[c8][1] = pkh(S[c8][2], S[c8][3]);
            }

            // ---- step-A exchange: swap lane bit4 with c8 bit0 ----
            unsigned FR[4][4];
            #pragma unroll
            for (int tau = 0; tau < 4; tau++) {
                #pragma unroll
                for (int rp = 0; rp < 2; rp++) {
                    unsigned X  = P2[2 * tau][rp];
                    unsigned Y  = P2[2 * tau + 1][rp];
                    unsigned Xs = (unsigned)__shfl_xor((int)X, 16);
                    unsigned Ys = (unsigned)__shfl_xor((int)Y, 16);
                    FR[tau][rp]     = hi4 ? Ys : X;   // slot s=0
                    FR[tau][2 + rp] = hi4 ? Y  : Xs;  // slot s=1
                }
            }

            // ---- PV: 4 k-slices of 32, V read with quad-swapped chunks --
            #pragma unroll
            for (int tau = 0; tau < 4; tau++) {
                union { unsigned u[4]; f16x8 v; } pu;
                pu.u[0] = FR[tau][0]; pu.u[1] = FR[tau][1];
                pu.u[2] = FR[tau][2]; pu.u[3] = FR[tau][3];
                f16x8 pf = pu.v;
                const int bf  = tau >> 1;
                const int rsP = (tau & 1) ? rp1 : rp0;
                __builtin_amdgcn_s_setprio(1);
                #pragma unroll
                for (int ct2 = 0; ct2 < 4; ct2++) {
                    f16x8 v = *(const f16x8*)&Vt_lds[bf][(ct2 * 16 + t) * 64 + rsP];
                    O[mt][ct2] = __builtin_amdgcn_mfma_f32_16x16x32_f16(pf, v, O[mt][ct2], 0, 0, 0);
                }
                Ol[mt] = __builtin_amdgcn_mfma_f32_16x16x32_f16(pf, ones, Ol[mt], 0, 0, 0);
                __builtin_amdgcn_s_setprio(0);
            }
        }
    }

    // epilogue: normalize, write [B][T][H*64] fp32 (O layout unchanged)
    #pragma unroll
    for (int mt = 0; mt < 2; mt++) {
        float* ob = out + ((size_t)b * TSEQ + qb * 128 + w * 32 + mt * 16 + quad * 4) * DMODEL
                  + h * 64;
        #pragma unroll
        for (int r = 0; r < 4; r++) {
            float inv = 1.0f / Ol[mt][r];
            #pragma unroll
            for (int ct2 = 0; ct2 < 4; ct2++)
                ob[(size_t)r * DMODEL + ct2 * 16 + t] = O[mt][ct2][r] * inv;
        }
    }
}

// ---------------------------------------------------------------------------
extern "C" void kernel_launch(void* const* d_in, const int* in_sizes, int n_in,
                              void* d_out, int out_size, void* d_ws, size_t ws_size,
                              hipStream_t stream)
{
    const float* x  = (const float*)d_in[0];
    const float* Wq = (const float*)d_in[1];
    const float* bq = (const float*)d_in[2];
    const float* Wk = (const float*)d_in[3];
    const float* bk = (const float*)d_in[4];
    const float* Wv = (const float*)d_in[5];
    const float* bv = (const float*)d_in[6];

    const size_t TEN = (size_t)MROWS * DMODEL;   // 8M
    const size_t WEN = (size_t)DMODEL * DMODEL;  // 1M
    _Float16* X16 = (_Float16*)d_ws;
    _Float16* Xr  = X16 + TEN;
    _Float16* Wf  = Xr + TEN;
    _Float16* Qh  = Wf + 3 * WEN;
    _Float16* Qr  = Qh + TEN;
    _Float16* Kh  = Qr + TEN;
    _Float16* Kr  = Kh + TEN;
    _Float16* VgT = Kr + TEN;
    float* out = (float*)d_out;

    int ncast = (X_F4 + 3 * W_F4) / 256;
    cast_all<<<ncast, 256, 0, stream>>>(x, Wq, Wk, Wv, X16, Xr, Wf);

    dim3 gg(DMODEL / 128, MROWS / 128, 3);
    qkv_gemm_mfma<<<gg, 256, 0, stream>>>(X16, Xr, Wf, bq, bk, bv,
                                          Qh, Qr, Kh, Kr, VgT);

    attn_fwd<<<1024, 256, 0, stream>>>(Qh, Qr, Kh, Kr, VgT, out);
}

// Round 12
// 292.773 us; speedup vs baseline: 1.0497x; 1.0497x over previous
//
#include <hip/hip_runtime.h>
#include <math.h>

#define TSEQ   2048
#define NBATCH 4
#define NHEAD  16
#define HDIM   64
#define DMODEL 1024
#define MROWS  (NBATCH * TSEQ)   // 8192
// fold 8 * log2(e) into Q so softmax runs in exp2 domain (v_exp_f32 native)
#define QSCALE 11.541560327111707f

typedef float f32x4  __attribute__((ext_vector_type(4)));
typedef _Float16 f16x8 __attribute__((ext_vector_type(8)));

// RNE f32 pair -> packed 2x f16 in a u32
static __device__ __forceinline__ unsigned pkh(float a, float b) {
    union { _Float16 h[2]; unsigned u; } z;
    z.h[0] = (_Float16)a; z.h[1] = (_Float16)b;
    return z.u;
}

// async global->LDS, 16B per lane; LDS dest = wave-uniform base + lane*16
static __device__ __forceinline__ void async_copy16(void* lds, const void* g) {
    __builtin_amdgcn_global_load_lds(
        (const __attribute__((address_space(1))) void*)g,
        (__attribute__((address_space(3))) void*)lds, 16, 0, 0);
}

// ---------------------------------------------------------------------------
// fp32 -> split-fp16 for X (hi + residual), fp16 for W.
// ---------------------------------------------------------------------------
#define X_F4 (MROWS * DMODEL / 4)          // 2097152
#define W_F4 (DMODEL * DMODEL / 4)         // 262144  (1<<18)
__global__ __launch_bounds__(256) void cast_all(
    const float* __restrict__ x,
    const float* __restrict__ wq, const float* __restrict__ wk,
    const float* __restrict__ wv,
    _Float16* __restrict__ X16, _Float16* __restrict__ Xr,
    _Float16* __restrict__ Wf)   // Wf [3][D][D]
{
    int gid = blockIdx.x * 256 + threadIdx.x;
    if (gid < X_F4) {
        float4 v = ((const float4*)x)[gid];
        float f[4] = {v.x, v.y, v.z, v.w};
        _Float16 h[4], r[4];
        #pragma unroll
        for (int c = 0; c < 4; c++) {
            h[c] = (_Float16)f[c];
            r[c] = (_Float16)(f[c] - (float)h[c]);
        }
        *(float2*)(X16 + (size_t)gid * 4) = *(const float2*)h;
        *(float2*)(Xr  + (size_t)gid * 4) = *(const float2*)r;
    } else {
        int rr = gid - X_F4;
        int z = rr >> 18;                  // 0..2
        int off = rr & (W_F4 - 1);
        const float* src = (z == 0) ? wq : (z == 1) ? wk : wv;
        _Float16* dst = Wf + (size_t)z * DMODEL * DMODEL;
        float4 v = ((const float4*)src)[off];
        _Float16 h[4] = {(_Float16)v.x, (_Float16)v.y, (_Float16)v.z, (_Float16)v.w};
        *(float2*)(dst + (size_t)off * 4) = *(const float2*)h;
    }
}

// ---------------------------------------------------------------------------
// Split-fp16 MFMA GEMM: Y = X W^T + b.  (R10 BK=64 structure, unchanged.)
// z0/z1: 2 MFMA (X16*W + Xr*W); z2 (V): 1 MFMA. XCD swizzle (T1) kept.
// ---------------------------------------------------------------------------
__global__ __launch_bounds__(256, 3) void qkv_gemm_mfma(
    const _Float16* __restrict__ X16, const _Float16* __restrict__ Xr,
    const _Float16* __restrict__ Wf3,
    const float* __restrict__ bq, const float* __restrict__ bk,
    const float* __restrict__ bv,
    _Float16* __restrict__ Qh, _Float16* __restrict__ Qr,
    _Float16* __restrict__ Kh, _Float16* __restrict__ Kr,
    _Float16* __restrict__ VgT)
{
    const int z = blockIdx.z;
    const bool dor = (z != 2);             // residual A-plane for Q,K only
    const _Float16* W = Wf3 + (size_t)z * DMODEL * DMODEL;
    const float* bias = (z == 0) ? bq : (z == 1) ? bk : bv;

    __shared__ __align__(16) _Float16 Ah[128 * 64];
    __shared__ __align__(16) _Float16 Ar[128 * 64];
    __shared__ __align__(16) _Float16 Bh[128 * 64];

    const int tid  = threadIdx.x;
    const int w    = tid >> 6;
    const int lane = tid & 63;
    const int t    = lane & 15;
    const int quad = lane >> 4;
    const int wm   = w >> 1, wn = w & 1;

    // XCD-chunked swizzle: orig in hw dispatch order (x fastest), 512 blocks
    const int orig = blockIdx.x + (blockIdx.y << 3);       // 0..511
    const int nw   = (orig & 7) * 64 + (orig >> 3);        // bijective remap
    const int bm   = (nw >> 3) * 128;                      // m-tile 0..63
    const int bn   = (nw & 7) * 128;                       // n-tile 0..7

    // staging geometry (attn pattern): 256 lanes x 16B = 32 rows of 128B/pass
    const int rl     = w * 8 + (lane >> 3);                // 0..31
    const int chsw   = (lane & 7) ^ ((lane >> 3) & 7);
    const int ld_off = (w * 8) * 64;                       // wave-uniform base

    // read slots: chunk g = kk*4 + quad at slot (g^(t&7))*8
    const int rq0 = ((0 * 4 + quad) ^ (t & 7)) * 8;
    const int rq1 = ((1 * 4 + quad) ^ (t & 7)) * 8;

    f32x4 acc[4][4];
    #pragma unroll
    for (int i = 0; i < 4; i++)
        #pragma unroll
        for (int j = 0; j < 4; j++) acc[i][j] = (f32x4){0.f, 0.f, 0.f, 0.f};

    for (int k0 = 0; k0 < DMODEL; k0 += 64) {
        __syncthreads();
        #pragma unroll
        for (int i = 0; i < 4; i++) {
            int row  = i * 32 + rl;
            int ldst = (i * 32) * 64 + ld_off;
            size_t ga = (size_t)(bm + row) * DMODEL + k0 + chsw * 8;
            size_t gb = (size_t)(bn + row) * DMODEL + k0 + chsw * 8;
            async_copy16(&Ah[ldst], X16 + ga);
            async_copy16(&Bh[ldst], W + gb);
            if (dor) async_copy16(&Ar[ldst], Xr + ga);
        }
        __syncthreads();

        #pragma unroll
        for (int kk = 0; kk < 2; kk++) {
            const int rq = kk ? rq1 : rq0;
            f16x8 ah[4], ar[4], bh[4];
            #pragma unroll
            for (int mt = 0; mt < 4; mt++) {
                int off = (wm * 64 + mt * 16 + t) * 64 + rq;
                ah[mt] = *(const f16x8*)&Ah[off];
                if (dor) ar[mt] = *(const f16x8*)&Ar[off];
            }
            #pragma unroll
            for (int nt = 0; nt < 4; nt++) {
                int off = (wn * 64 + nt * 16 + t) * 64 + rq;
                bh[nt] = *(const f16x8*)&Bh[off];
            }
            #pragma unroll
            for (int mt = 0; mt < 4; mt++)
                #pragma unroll
                for (int nt = 0; nt < 4; nt++) {
                    if (dor)
                        acc[mt][nt] = __builtin_amdgcn_mfma_f32_16x16x32_f16(
                            ar[mt], bh[nt], acc[mt][nt], 0, 0, 0);
                    acc[mt][nt] = __builtin_amdgcn_mfma_f32_16x16x32_f16(
                        ah[mt], bh[nt], acc[mt][nt], 0, 0, 0);
                }
        }
    }

    const float scale = (z == 0) ? QSCALE : 1.0f;
    const int n_base = bn + wn * 64;
    const int h_head = n_base >> 6;
    float bvs[4];
    #pragma unroll
    for (int nt = 0; nt < 4; nt++)
        bvs[nt] = bias[n_base + nt * 16 + t];

    #pragma unroll
    for (int mt = 0; mt < 4; mt++) {
        #pragma unroll
        for (int r = 0; r < 4; r++) {
            int m  = bm + wm * 64 + mt * 16 + quad * 4 + r;
            int b_ = m >> 11;
            int t_ = m & 2047;
            #pragma unroll
            for (int nt = 0; nt < 4; nt++) {
                int d = nt * 16 + t;
                float v = (acc[mt][nt][r] + bvs[nt]) * scale;
                if (z == 2) {
                    size_t idx = ((size_t)(b_ * NHEAD + h_head) * HDIM + d) * TSEQ + t_;
                    VgT[idx] = (_Float16)v;
                } else {
                    size_t idx = (((size_t)(b_ * NHEAD + h_head) * TSEQ + t_) << 6) + d;
                    _Float16 hb = (_Float16)v;
                    _Float16 rb = (_Float16)(v - (float)hb);
                    if (z == 0) { Qh[idx] = hb; Qr[idx] = rb; }
                    else        { Kh[idx] = hb; Kr[idx] = rb; }
                }
            }
        }
    }
}

// ---------------------------------------------------------------------------
// MFMA flash attention v12 — R10's proven v10 inner loop (shfl_xor P
// exchange), plus persistent-zero first-MFMA C operand (safe codegen-only).
// R11 RETREAT: v_permlane16_swap_b32 inline-asm produced NaN (hardware did
// not produce the modeled two-output swap; exchange became non-bijective,
// zeroing some denominators). The required exchange is intrinsically a
// lane-bit-4 crossing, so permlane32_swap cannot substitute. shfl_xor it is.
// LDS: 2*(8+8+8) = 48 KB -> 3 blocks/CU; 1024-block heavy-first grid.
// ---------------------------------------------------------------------------
__global__ __launch_bounds__(256, 3) void attn_fwd(
    const _Float16* __restrict__ Qh, const _Float16* __restrict__ Qr,
    const _Float16* __restrict__ Kh, const _Float16* __restrict__ Kr,
    const _Float16* __restrict__ VgT,   // [bh][64][T]
    float* __restrict__ out)            // [B][T][1024]
{
    __shared__ __align__(16) _Float16 Kh_lds[2][64 * 64];
    __shared__ __align__(16) _Float16 Kr_lds[2][64 * 64];
    __shared__ __align__(16) _Float16 Vt_lds[2][64 * 64];

    const int tid  = threadIdx.x;

    // heavy-first XCD-chunked mapping over 1024 blocks
    const int l    = blockIdx.x;
    const int xcd  = l & 7;
    const int idx  = l >> 3;                 // 0..127
    const int bh   = xcd * 8 + (idx & 7);    // 0..63
    const int qb   = 15 - (idx >> 3);        // 15..0 (heavy first)

    const int b    = bh >> 4, h = bh & 15;
    const int w    = tid >> 6;
    const int lane = tid & 63;
    const int t    = lane & 15;
    const int quad = lane >> 4;

    // staging geometry: per round, 256 lanes x 16B = 32 rows of 128B.
    const int rl      = w * 8 + (lane >> 3);         // 0..31 within round
    const int chsw    = (lane & 7) ^ ((lane >> 3) & 7);
    const int ld_off  = (w * 8) * 64;                // wave-uniform LDS base

    const size_t kbase = (size_t)bh * TSEQ;          // K rows
    const size_t vbase = (size_t)bh * HDIM;          // V^T rows

    // K read chunks: logical chunk g = dh*4+quad at slot g^(t&7)
    const int rs0 = ((0 * 4 + quad) ^ (t & 7)) * 8;
    const int rs1 = ((1 * 4 + quad) ^ (t & 7)) * 8;
    // V read chunks for PV: quad bits SWAPPED (absorbs the 2nd exchange step)
    const int qsw = ((quad & 1) << 1) | (quad >> 1);
    const int rp0 = ((0 * 4 + qsw) ^ (t & 7)) * 8;
    const int rp1 = ((1 * 4 + qsw) ^ (t & 7)) * 8;
    const bool hi4 = (quad & 1);                     // lane bit4

    f16x8 ones;
    #pragma unroll
    for (int i = 0; i < 8; i++) ones[i] = (_Float16)1.0f;
    const f32x4 FZ = (f32x4){0.f, 0.f, 0.f, 0.f};    // persistent zero C

    auto stage = [&](int kt, int bf) {
        #pragma unroll
        for (int i = 0; i < 2; i++) {
            int row = i * 32 + rl;
            const _Float16* gk = Kh + (kbase + kt * 64 + row) * 64 + chsw * 8;
            async_copy16(&Kh_lds[bf][(i * 32) * 64 + ld_off], gk);
            const _Float16* gr = Kr + (kbase + kt * 64 + row) * 64 + chsw * 8;
            async_copy16(&Kr_lds[bf][(i * 32) * 64 + ld_off], gr);
            const _Float16* gv = VgT + (vbase + row) * TSEQ + kt * 64 + chsw * 8;
            async_copy16(&Vt_lds[bf][(i * 32) * 64 + ld_off], gv);
        }
    };

    // Q frags (used as B-operand in swapped QK^T)
    f16x8 qh[2][2], qr[2][2];
    #pragma unroll
    for (int mt = 0; mt < 2; mt++) {
        size_t qrow = kbase + qb * 128 + w * 32 + mt * 16 + t;
        #pragma unroll
        for (int dh = 0; dh < 2; dh++) {
            qh[mt][dh] = *(const f16x8*)(Qh + qrow * 64 + dh * 32 + quad * 8);
            qr[mt][dh] = *(const f16x8*)(Qr + qrow * 64 + dh * 32 + quad * 8);
        }
    }

    f32x4 O[2][4], Ol[2];
    #pragma unroll
    for (int mt = 0; mt < 2; mt++) {
        Ol[mt] = (f32x4){0.f, 0.f, 0.f, 0.f};
        #pragma unroll
        for (int j = 0; j < 4; j++) O[mt][j] = (f32x4){0.f, 0.f, 0.f, 0.f};
    }
    float m_st[2];
    m_st[0] = -1e30f; m_st[1] = -1e30f;

    const int npair = qb + 1;

    #pragma unroll 1
    for (int p = 0; p < npair; p++) {
        __syncthreads();              // previous pair's LDS reads complete
        stage(2 * p, 0);
        stage(2 * p + 1, 1);
        __syncthreads();              // drain the 12 async copies

        #pragma unroll
        for (int mt = 0; mt < 2; mt++) {
            // ---- S^T over 128 kv: S[c8][r] = S[kp=c8*16+quad*4+r][q=t]
            f32x4 S[8];
            __builtin_amdgcn_s_setprio(1);
            #pragma unroll
            for (int c8 = 0; c8 < 8; c8++) {
                const int bf = c8 >> 2;
                const int rowoff = ((c8 & 3) * 16 + t) * 64;
                {
                    f16x8 kh = *(const f16x8*)&Kh_lds[bf][rowoff + rs0];
                    f16x8 kr = *(const f16x8*)&Kr_lds[bf][rowoff + rs0];
                    S[c8] = __builtin_amdgcn_mfma_f32_16x16x32_f16(kh, qr[mt][0], FZ, 0, 0, 0);
                    S[c8] = __builtin_amdgcn_mfma_f32_16x16x32_f16(kr, qh[mt][0], S[c8], 0, 0, 0);
                    S[c8] = __builtin_amdgcn_mfma_f32_16x16x32_f16(kh, qh[mt][0], S[c8], 0, 0, 0);
                }
                {
                    f16x8 kh = *(const f16x8*)&Kh_lds[bf][rowoff + rs1];
                    f16x8 kr = *(const f16x8*)&Kr_lds[bf][rowoff + rs1];
                    S[c8] = __builtin_amdgcn_mfma_f32_16x16x32_f16(kh, qr[mt][1], S[c8], 0, 0, 0);
                    S[c8] = __builtin_amdgcn_mfma_f32_16x16x32_f16(kr, qh[mt][1], S[c8], 0, 0, 0);
                    S[c8] = __builtin_amdgcn_mfma_f32_16x16x32_f16(kh, qh[mt][1], S[c8], 0, 0, 0);
                }
            }
            __builtin_amdgcn_s_setprio(0);

            // causal mask: kp > q  (only the diagonal pair)
            if (p == qb) {
                const int qloc = w * 32 + mt * 16 + t;
                #pragma unroll
                for (int c8 = 0; c8 < 8; c8++) {
                    int kp = c8 * 16 + quad * 4;
                    #pragma unroll
                    for (int r = 0; r < 4; r++)
                        if (kp + r > qloc) S[c8][r] = -1e30f;
                }
            }

            // ---- row max: in-lane over 32 + cross-quad (2 shfl) ----
            float mx = S[0][0];
            #pragma unroll
            for (int c8 = 0; c8 < 8; c8++)
                #pragma unroll
                for (int r = 0; r < 4; r++)
                    mx = fmaxf(mx, S[c8][r]);
            mx = fmaxf(mx, __shfl_xor(mx, 16));
            mx = fmaxf(mx, __shfl_xor(mx, 32));

            // ---- defer-max rescale (THR=8 in exp2 domain) ----
            bool need = mx > m_st[mt] + 8.0f;
            if (__ballot(need)) {
                float mn = fmaxf(m_st[mt], mx);
                float al = exp2f(m_st[mt] - mn);
                m_st[mt] = mn;
                #pragma unroll
                for (int r = 0; r < 4; r++) {
                    // O rows live at q = quad*4+r; al lives at lane t=q
                    float a = __shfl(al, (lane & 48) + quad * 4 + r);
                    Ol[mt][r] *= a;
                    #pragma unroll
                    for (int ct2 = 0; ct2 < 4; ct2++) O[mt][ct2][r] *= a;
                }
            }

            #pragma unroll
            for (int c8 = 0; c8 < 8; c8++)
                #pragma unroll
                for (int r = 0; r < 4; r++)
                    S[c8][r] = exp2f(S[c8][r] - m_st[mt]);

            // ---- pack P to f16 pairs: P2[c8][rp] = (r=2rp, r=2rp+1) ----
            unsigned P2[8][2];
            #pragma unroll
            for (int c8 = 0; c8 < 8; c8++) {
                P2[c8][0] = pkh(S[c8][0], S[c8][1]);
                P2[c8][1] = pkh(S[c8][2], S[c8][3]);
            }

            // ---- step-A exchange: swap lane bit4 with c8 bit0 (shfl) ----
            unsigned FR[4][4];
            #pragma unroll
            for (int tau = 0; tau < 4; tau++) {
                #pragma unroll
                for (int rp = 0; rp < 2; rp++) {
                    unsigned X  = P2[2 * tau][rp];
                    unsigned Y  = P2[2 * tau + 1][rp];
                    unsigned Xs = (unsigned)__shfl_xor((int)X, 16);
                    unsigned Ys = (unsigned)__shfl_xor((int)Y, 16);
                    FR[tau][rp]     = hi4 ? Ys : X;   // slot s=0
                    FR[tau][2 + rp] = hi4 ? Y  : Xs;  // slot s=1
                }
            }

            // ---- PV: 4 k-slices of 32, V read with quad-swapped chunks --
            #pragma unroll
            for (int tau = 0; tau < 4; tau++) {
                union { unsigned u[4]; f16x8 v; } pu;
                pu.u[0] = FR[tau][0]; pu.u[1] = FR[tau][1];
                pu.u[2] = FR[tau][2]; pu.u[3] = FR[tau][3];
                f16x8 pf = pu.v;
                const int bf  = tau >> 1;
                const int rsP = (tau & 1) ? rp1 : rp0;
                __builtin_amdgcn_s_setprio(1);
                #pragma unroll
                for (int ct2 = 0; ct2 < 4; ct2++) {
                    f16x8 v = *(const f16x8*)&Vt_lds[bf][(ct2 * 16 + t) * 64 + rsP];
                    O[mt][ct2] = __builtin_amdgcn_mfma_f32_16x16x32_f16(pf, v, O[mt][ct2], 0, 0, 0);
                }
                Ol[mt] = __builtin_amdgcn_mfma_f32_16x16x32_f16(pf, ones, Ol[mt], 0, 0, 0);
                __builtin_amdgcn_s_setprio(0);
            }
        }
    }

    // epilogue: normalize, write [B][T][H*64] fp32 (O layout unchanged)
    #pragma unroll
    for (int mt = 0; mt < 2; mt++) {
        float* ob = out + ((size_t)b * TSEQ + qb * 128 + w * 32 + mt * 16 + quad * 4) * DMODEL
                  + h * 64;
        #pragma unroll
        for (int r = 0; r < 4; r++) {
            float inv = 1.0f / Ol[mt][r];
            #pragma unroll
            for (int ct2 = 0; ct2 < 4; ct2++)
                ob[(size_t)r * DMODEL + ct2 * 16 + t] = O[mt][ct2][r] * inv;
        }
    }
}

// ---------------------------------------------------------------------------
extern "C" void kernel_launch(void* const* d_in, const int* in_sizes, int n_in,
                              void* d_out, int out_size, void* d_ws, size_t ws_size,
                              hipStream_t stream)
{
    const float* x  = (const float*)d_in[0];
    const float* Wq = (const float*)d_in[1];
    const float* bq = (const float*)d_in[2];
    const float* Wk = (const float*)d_in[3];
    const float* bk = (const float*)d_in[4];
    const float* Wv = (const float*)d_in[5];
    const float* bv = (const float*)d_in[6];

    const size_t TEN = (size_t)MROWS * DMODEL;   // 8M
    const size_t WEN = (size_t)DMODEL * DMODEL;  // 1M
    _Float16* X16 = (_Float16*)d_ws;
    _Float16* Xr  = X16 + TEN;
    _Float16* Wf  = Xr + TEN;
    _Float16* Qh  = Wf + 3 * WEN;
    _Float16* Qr  = Qh + TEN;
    _Float16* Kh  = Qr + TEN;
    _Float16* Kr  = Kh + TEN;
    _Float16* VgT = Kr + TEN;
    float* out = (float*)d_out;

    int ncast = (X_F4 + 3 * W_F4) / 256;
    cast_all<<<ncast, 256, 0, stream>>>(x, Wq, Wk, Wv, X16, Xr, Wf);

    dim3 gg(DMODEL / 128, MROWS / 128, 3);
    qkv_gemm_mfma<<<gg, 256, 0, stream>>>(X16, Xr, Wf, bq, bk, bv,
                                          Qh, Qr, Kh, Kr, VgT);

    attn_fwd<<<1024, 256, 0, stream>>>(Qh, Qr, Kh, Kr, VgT, out);
}